// Round 12
// baseline (16.547 us; speedup 1.0000x reference)
//
#include <hip/hip_runtime.h>
#include <math.h>

#define D 512
#define NREL 512
#define NB 1024

typedef _Float16 f16x8 __attribute__((ext_vector_type(8)));
typedef float f32x4 __attribute__((ext_vector_type(4)));

__device__ __forceinline__ float wave_sum(float v) {
#pragma unroll
    for (int m = 1; m < 64; m <<= 1) v += __shfl_xor(v, m, 64);
    return v;
}
__device__ __forceinline__ void wave_sum3(float& a, float& b, float& c) {
#pragma unroll
    for (int m = 1; m < 64; m <<= 1) {   // 3 independent chains interleaved
        a += __shfl_xor(a, m, 64);
        b += __shfl_xor(b, m, 64);
        c += __shfl_xor(c, m, 64);
    }
}
// tanh(x)/x and atanh(x)/x as even polynomials in u = x^2.
// Here x = 0.1*||row|| <= ~0.05 -> u <= 0.0025; truncation error < 1e-8 (fp32-exact).
__device__ __forceinline__ float tanhc(float u) {
    return 1.0f + u * (-0.33333333f + u * (0.13333333f - u * 0.05396825f));
}
__device__ __forceinline__ float atanhc(float u) {
    return 1.0f + u * (0.33333333f + u * (0.2f + u * 0.14285714f));
}

// ---- one wave: rel_hyp row r -> B3 (fp16), y2[r] ----------------------------
__device__ __forceinline__ void prep_rel_row(
        int r, int lane, const float* __restrict__ rel,
        _Float16* __restrict__ B3, float* __restrict__ y2) {
    const float* src = rel + (size_t)r * D + lane * 8;
    const float4 u0 = *(const float4*)src;
    const float4 u1 = *(const float4*)(src + 4);
    const float uu = wave_sum(u0.x*u0.x + u0.y*u0.y + u0.z*u0.z + u0.w*u0.w
                            + u1.x*u1.x + u1.y*u1.y + u1.z*u1.z + u1.w*u1.w);
    const float es = tanhc(0.01f * uu);          // tanh(0.1 n)/(0.1 n), sqrt-free
    f16x8 h;
    h[0] = (_Float16)(es*u0.x); h[1] = (_Float16)(es*u0.y);
    h[2] = (_Float16)(es*u0.z); h[3] = (_Float16)(es*u0.w);
    h[4] = (_Float16)(es*u1.x); h[5] = (_Float16)(es*u1.y);
    h[6] = (_Float16)(es*u1.z); h[7] = (_Float16)(es*u1.w);
    *(f16x8*)(B3 + (size_t)r * D + lane * 8) = h;
    if (lane == 0) y2[r] = es * es * uu;
}

// ---- one wave: query row b -> A3 (fp16), x2[b] ------------------------------
__device__ __forceinline__ void prep_q_row(
        int b, int lane,
        const float* __restrict__ ent, const int* __restrict__ trip,
        const float* __restrict__ grot,
        _Float16* __restrict__ A3, float* __restrict__ x2) {
    const float c = 0.01f;
    const int si = trip[3 * b], oi = trip[3 * b + 2];
    const float* ps = ent + (size_t)si * D + lane * 8;
    const float* po = ent + (size_t)oi * D + lane * 8;
    const float4 s0 = *(const float4*)ps, s1 = *(const float4*)(ps + 4);
    const float4 o0 = *(const float4*)po, o1 = *(const float4*)(po + 4);

    // rotation of RAW s (ls folded in later: u = R(ls*s) = ls*R(s))
    const float4 ang = *(const float4*)(grot + 4 * lane);
    const float ca0 = __cosf(ang.x), sa0 = __sinf(ang.x);
    const float ca1 = __cosf(ang.y), sa1 = __sinf(ang.y);
    const float ca2 = __cosf(ang.z), sa2 = __sinf(ang.z);
    const float ca3 = __cosf(ang.w), sa3 = __sinf(ang.w);
    const float rx0 = ca0*s0.x - sa0*s0.y, ry0 = sa0*s0.x + ca0*s0.y;
    const float rx1 = ca1*s0.z - sa1*s0.w, ry1 = sa1*s0.z + ca1*s0.w;
    const float rx2 = ca2*s1.x - sa2*s1.y, ry2 = sa2*s1.x + ca2*s1.y;
    const float rx3 = ca3*s1.z - sa3*s1.w, ry3 = sa3*s1.z + ca3*s1.w;

    // three independent reductions, interleaved for ILP
    float ss = s0.x*s0.x + s0.y*s0.y + s0.z*s0.z + s0.w*s0.w
             + s1.x*s1.x + s1.y*s1.y + s1.z*s1.z + s1.w*s1.w;
    float oo = o0.x*o0.x + o0.y*o0.y + o0.z*o0.z + o0.w*o0.w
             + o1.x*o1.x + o1.y*o1.y + o1.z*o1.z + o1.w*o1.w;
    float rw = rx0*o0.x + ry0*o0.y + rx1*o0.z + ry1*o0.w
             + rx2*o1.x + ry2*o1.y + rx3*o1.z + ry3*o1.w;   // R(s).o
    wave_sum3(ss, oo, rw);

    // scalar chain (sqrt-free): ls = atanh(.1 n)/(.1 n); es = tanh(.1 n_u)/(.1 n_u)
    const float ls  = atanhc(c * ss);
    const float nu2 = ls * ls * ss;              // ||u||^2
    const float es  = tanhc(c * nu2);
    const float rr  = es * es * nu2;             // ||rot_s||^2
    const float ro  = es * ls * rw;              // rot_s . o
    const float A1  = 1.0f - 2.0f*c*ro + c*oo;
    const float B1  = 1.0f - c*rr;
    const float den = fmaxf(1.0f - 2.0f*c*ro + c*c*rr*oo, 1e-15f);
    const float inv = 1.0f / den;
    const float qa  = -A1 * es * ls * inv;       // multiplies R(s)
    const float qb  = B1 * inv;
    f16x8 h;
    h[0] = (_Float16)(qa*rx0 + qb*o0.x); h[1] = (_Float16)(qa*ry0 + qb*o0.y);
    h[2] = (_Float16)(qa*rx1 + qb*o0.z); h[3] = (_Float16)(qa*ry1 + qb*o0.w);
    h[4] = (_Float16)(qa*rx2 + qb*o1.x); h[5] = (_Float16)(qa*ry2 + qb*o1.y);
    h[6] = (_Float16)(qa*rx3 + qb*o1.z); h[7] = (_Float16)(qa*ry3 + qb*o1.w);
    *(f16x8*)(A3 + (size_t)b * D + lane * 8) = h;
    if (lane == 0)
        x2[b] = (A1*A1*rr - 2.0f*A1*B1*ro + B1*B1*oo) * inv * inv;
}

// ---- prep: 1536 waves; rel/q interleaved within blocks for tail balance ----
__global__ __launch_bounds__(256) void prep_kernel(
        const float* __restrict__ ent, const float* __restrict__ rel,
        const int* __restrict__ trip, const float* __restrict__ grot,
        _Float16* __restrict__ A3, _Float16* __restrict__ B3,
        float* __restrict__ x2, float* __restrict__ y2) {
    const int t = threadIdx.x, wid = t >> 6, lane = t & 63;
    const int gid = blockIdx.x * 4 + wid;        // 0..1535
    const int g3 = gid / 3;
    if (gid % 3 == 0) prep_rel_row(g3, lane, rel, B3, y2);
    else              prep_q_row(gid - g3 - 1, lane, ent, trip, grot, A3, x2);
}

// ---- score: 64x32 tile / 512-thr block; 8 waves = 2 m-halves x 4 K-quarters
__global__ __launch_bounds__(512) void score_mfma(
        const _Float16* __restrict__ A3, const _Float16* __restrict__ B3,
        const float* __restrict__ x2, const float* __restrict__ y2,
        const float* __restrict__ bias, float* __restrict__ out) {
    const int t = threadIdx.x, wid = t >> 6, lane = t & 63;
    const int wm = wid & 1, kh = wid >> 1;       // kh in 0..3
    const int m0 = blockIdx.y * 64 + wm * 32;
    const int n0 = blockIdx.x * 32;
    const int row = lane & 15, kg = lane >> 4;

    const f16x8* pa0 = (const f16x8*)(A3 + (size_t)(m0 + row) * D) + kg;
    const f16x8* pa1 = (const f16x8*)(A3 + (size_t)(m0 + 16 + row) * D) + kg;
    const f16x8* pb0 = (const f16x8*)(B3 + (size_t)(n0 + row) * D) + kg;
    const f16x8* pb1 = (const f16x8*)(B3 + (size_t)(n0 + 16 + row) * D) + kg;

    f32x4 acc[2][2] = {};
    const int k8beg = kh * 16;                   // K=128 per wave
#pragma unroll
    for (int k8 = k8beg; k8 < k8beg + 16; k8 += 4) {  // 4 iters, unrolled
        const f16x8 a0 = pa0[k8], a1 = pa1[k8];
        const f16x8 b0 = pb0[k8], b1 = pb1[k8];
        acc[0][0] = __builtin_amdgcn_mfma_f32_16x16x32_f16(a0, b0, acc[0][0], 0, 0, 0);
        acc[0][1] = __builtin_amdgcn_mfma_f32_16x16x32_f16(a0, b1, acc[0][1], 0, 0, 0);
        acc[1][0] = __builtin_amdgcn_mfma_f32_16x16x32_f16(a1, b0, acc[1][0], 0, 0, 0);
        acc[1][1] = __builtin_amdgcn_mfma_f32_16x16x32_f16(a1, b1, acc[1][1], 0, 0, 0);
    }

    __shared__ f32x4 lacc[3][2][64][4];          // partials from kh=1..3
    if (kh > 0) {
#pragma unroll
        for (int i = 0; i < 2; ++i)
#pragma unroll
            for (int j = 0; j < 2; ++j)
                lacc[kh - 1][wm][lane][i * 2 + j] = acc[i][j];
    }
    __syncthreads();
    if (kh == 0) {
#pragma unroll
        for (int p = 0; p < 3; ++p)
#pragma unroll
            for (int i = 0; i < 2; ++i)
#pragma unroll
                for (int j = 0; j < 2; ++j)
                    acc[i][j] += lacc[p][wm][lane][i * 2 + j];

        // C/D layout: col = lane&15, row = (lane>>4)*4 + reg
        const float c = 0.01f;
        const int crow = (lane >> 4) * 4;
        const int ccol = lane & 15;
#pragma unroll
        for (int i = 0; i < 2; ++i) {
#pragma unroll
            for (int r = 0; r < 4; ++r) {
                const int m = m0 + i * 16 + crow + r;
                const float X2 = x2[m];
                const float B1 = 1.0f - c * X2;
#pragma unroll
                for (int j = 0; j < 2; ++j) {
                    const int n  = n0 + j * 16 + ccol;
                    const float qd = acc[i][j][r];
                    const float Y2 = y2[n];
                    const float A1  = 1.0f - 2.0f * c * qd + c * Y2;
                    const float den = fmaxf(1.0f - 2.0f * c * qd + c * c * X2 * Y2, 1e-15f);
                    const float num2 = A1 * A1 * X2 - 2.0f * A1 * B1 * qd + B1 * B1 * Y2;
                    out[(size_t)m * NREL + n] = -(num2 / (den * den)) + bias[n];
                }
            }
        }
    }
}

extern "C" void kernel_launch(void* const* d_in, const int* in_sizes, int n_in,
                              void* d_out, int out_size, void* d_ws, size_t ws_size,
                              hipStream_t stream) {
    const float* ent  = (const float*)d_in[0];   // (20000, 512)
    const float* rel  = (const float*)d_in[1];   // (512, 512)
    const int*   trip = (const int*)d_in[2];     // (1024, 3)
    const float* grot = (const float*)d_in[3];   // (256,)
    const float* bias = (const float*)d_in[4];   // (512,)
    float* out = (float*)d_out;                  // (1024, 512)

    _Float16* A3 = (_Float16*)d_ws;              // 1024*512 fp16
    _Float16* B3 = A3 + (size_t)NB * D;          // 512*512 fp16
    float* x2 = (float*)(B3 + (size_t)NREL * D);
    float* y2 = x2 + NB;

    prep_kernel<<<dim3((NREL + NB) / 4), dim3(256), 0, stream>>>(
        ent, rel, trip, grot, A3, B3, x2, y2);
    score_mfma<<<dim3(NREL / 32, NB / 64), dim3(512), 0, stream>>>(
        A3, B3, x2, y2, bias, out);
}

// Round 13
// 14.986 us; speedup vs baseline: 1.1042x; 1.1042x over previous
//
#include <hip/hip_runtime.h>
#include <math.h>

#define D 512
#define NREL 512
#define NB 1024

typedef _Float16 f16x8 __attribute__((ext_vector_type(8)));
typedef float f32x4 __attribute__((ext_vector_type(4)));

// tanh(x)/x and atanh(x)/x as even polynomials in u = x^2 (x = 0.1*||row|| <= ~0.05,
// u <= 0.0025; truncation error < 1e-8, fp32-exact).
__device__ __forceinline__ float tanhc(float u) {
    return 1.0f + u * (-0.33333333f + u * (0.13333333f - u * 0.05396825f));
}
__device__ __forceinline__ float atanhc(float u) {
    return 1.0f + u * (0.33333333f + u * (0.2f + u * 0.14285714f));
}

template <int N>
__device__ __forceinline__ void wave_sum_n(float* v) {
#pragma unroll
    for (int m = 1; m < 64; m <<= 1) {
#pragma unroll
        for (int i = 0; i < N; ++i) v[i] += __shfl_xor(v[i], m, 64);
    }
}

// Single dispatch: block (bn,bm) = 32m x 64n output tile, fully self-sufficient.
// Phase A: prep 32 q-rows + 64 rel-rows into swizzled LDS (fp16). Local barrier.
// Phase B: per-wave 16x16 MFMA GEMM over K=512 from LDS + fused epilogue.
__global__ __launch_bounds__(512, 2) void fused_kernel(
        const float* __restrict__ ent, const float* __restrict__ rel,
        const int* __restrict__ trip, const float* __restrict__ grot,
        const float* __restrict__ bias, float* __restrict__ out) {
    extern __shared__ char smem[];
    _Float16* Bls = (_Float16*)smem;            // 64 x 512 fp16 (swizzled)
    _Float16* Als = Bls + 64 * 512;             // 32 x 512 fp16 (swizzled)
    float* x2s = (float*)(Als + 32 * 512);      // 32
    float* y2s = x2s + 32;                      // 64

    const int t = threadIdx.x, wid = t >> 6, lane = t & 63;
    const int n0 = blockIdx.x * 64;             // 8 n-tiles
    const int m0 = blockIdx.y * 32;             // 32 m-tiles
    const float c = 0.01f;

    // ================= phase A =================
    // rel loads first (independent, in flight early)
    float rv[8][8];
#pragma unroll
    for (int j = 0; j < 8; ++j) {
        const int r = n0 + wid * 8 + j;
        const float4 a0 = *(const float4*)(rel + (size_t)r * D + lane * 8);
        const float4 a1 = *(const float4*)(rel + (size_t)r * D + lane * 8 + 4);
        rv[j][0] = a0.x; rv[j][1] = a0.y; rv[j][2] = a0.z; rv[j][3] = a0.w;
        rv[j][4] = a1.x; rv[j][5] = a1.y; rv[j][6] = a1.z; rv[j][7] = a1.w;
    }
    // q loads
    float sv[4][8], ov[4][8];
#pragma unroll
    for (int i = 0; i < 4; ++i) {
        const int b = m0 + wid * 4 + i;
        const int si = trip[3 * b], oi = trip[3 * b + 2];
        const float4 a0 = *(const float4*)(ent + (size_t)si * D + lane * 8);
        const float4 a1 = *(const float4*)(ent + (size_t)si * D + lane * 8 + 4);
        const float4 b0 = *(const float4*)(ent + (size_t)oi * D + lane * 8);
        const float4 b1 = *(const float4*)(ent + (size_t)oi * D + lane * 8 + 4);
        sv[i][0] = a0.x; sv[i][1] = a0.y; sv[i][2] = a0.z; sv[i][3] = a0.w;
        sv[i][4] = a1.x; sv[i][5] = a1.y; sv[i][6] = a1.z; sv[i][7] = a1.w;
        ov[i][0] = b0.x; ov[i][1] = b0.y; ov[i][2] = b0.z; ov[i][3] = b0.w;
        ov[i][4] = b1.x; ov[i][5] = b1.y; ov[i][6] = b1.z; ov[i][7] = b1.w;
    }
    // rotation of raw s (ls folded in later by linearity)
    const float4 ang = *(const float4*)(grot + 4 * lane);
    const float ca0 = __cosf(ang.x), sa0 = __sinf(ang.x);
    const float ca1 = __cosf(ang.y), sa1 = __sinf(ang.y);
    const float ca2 = __cosf(ang.z), sa2 = __sinf(ang.z);
    const float ca3 = __cosf(ang.w), sa3 = __sinf(ang.w);
    float rt[4][8];
#pragma unroll
    for (int i = 0; i < 4; ++i) {
        rt[i][0] = ca0 * sv[i][0] - sa0 * sv[i][1];
        rt[i][1] = sa0 * sv[i][0] + ca0 * sv[i][1];
        rt[i][2] = ca1 * sv[i][2] - sa1 * sv[i][3];
        rt[i][3] = sa1 * sv[i][2] + ca1 * sv[i][3];
        rt[i][4] = ca2 * sv[i][4] - sa2 * sv[i][5];
        rt[i][5] = sa2 * sv[i][4] + ca2 * sv[i][5];
        rt[i][6] = ca3 * sv[i][6] - sa3 * sv[i][7];
        rt[i][7] = sa3 * sv[i][6] + ca3 * sv[i][7];
    }
    // 20 interleaved reductions: q (ss,oo,rw)x4 + rel (uu)x8
    float v[20];
#pragma unroll
    for (int i = 0; i < 4; ++i) {
        float ss = 0.f, oo = 0.f, rw = 0.f;
#pragma unroll
        for (int k = 0; k < 8; ++k) {
            ss += sv[i][k] * sv[i][k];
            oo += ov[i][k] * ov[i][k];
            rw += rt[i][k] * ov[i][k];
        }
        v[3 * i] = ss; v[3 * i + 1] = oo; v[3 * i + 2] = rw;
    }
#pragma unroll
    for (int j = 0; j < 8; ++j) {
        float uu = 0.f;
#pragma unroll
        for (int k = 0; k < 8; ++k) uu += rv[j][k] * rv[j][k];
        v[12 + j] = uu;
    }
    wave_sum_n<20>(v);

    // q scalar chains + pack + swizzled LDS store
#pragma unroll
    for (int i = 0; i < 4; ++i) {
        const float ss = v[3 * i], oo = v[3 * i + 1], rw = v[3 * i + 2];
        const float ls  = atanhc(c * ss);
        const float nu2 = ls * ls * ss;
        const float es  = tanhc(c * nu2);
        const float rr  = es * es * nu2;
        const float ro  = es * ls * rw;
        const float A1  = 1.0f - 2.0f * c * ro + c * oo;
        const float B1  = 1.0f - c * rr;
        const float den = fmaxf(1.0f - 2.0f * c * ro + c * c * rr * oo, 1e-15f);
        const float inv = 1.0f / den;
        const float qa  = -A1 * es * ls * inv;
        const float qb  = B1 * inv;
        f16x8 h;
#pragma unroll
        for (int k = 0; k < 8; ++k) h[k] = (_Float16)(qa * rt[i][k] + qb * ov[i][k]);
        const int lr = wid * 4 + i;             // local A row 0..31
        *(f16x8*)(Als + lr * 512 + ((lane * 8) ^ ((lr & 7) << 3))) = h;
        if (lane == 0)
            x2s[lr] = (A1 * A1 * rr - 2.0f * A1 * B1 * ro + B1 * B1 * oo) * inv * inv;
    }
    // rel scalar chains + pack + swizzled LDS store
#pragma unroll
    for (int j = 0; j < 8; ++j) {
        const float uu = v[12 + j];
        const float es = tanhc(c * uu);
        f16x8 h;
#pragma unroll
        for (int k = 0; k < 8; ++k) h[k] = (_Float16)(es * rv[j][k]);
        const int lr = wid * 8 + j;             // local B row 0..63
        *(f16x8*)(Bls + lr * 512 + ((lane * 8) ^ ((lr & 7) << 3))) = h;
        if (lane == 0) y2s[lr] = es * es * uu;
    }

    __syncthreads();                            // local barrier only

    // ================= phase B =================
    const int wm = wid & 1, wn = wid >> 1;      // 2m x 4n wave grid
    const int rA = wm * 16 + (lane & 15);
    const int rB = wn * 16 + (lane & 15);
    const int kg = lane >> 4;
    const _Float16* pa = Als + rA * 512;
    const _Float16* pb = Bls + rB * 512;
    const int xa = (rA & 7) << 3, xb = (rB & 7) << 3;

    f32x4 acc = {};
#pragma unroll
    for (int ks = 0; ks < 16; ++ks) {
        const int ko = ks * 32 + kg * 8;
        const f16x8 a = *(const f16x8*)(pa + (ko ^ xa));
        const f16x8 b = *(const f16x8*)(pb + (ko ^ xb));
        acc = __builtin_amdgcn_mfma_f32_16x16x32_f16(a, b, acc, 0, 0, 0);
    }

    // epilogue: C/D layout col = lane&15, row = (lane>>4)*4 + reg
    const int crow = (lane >> 4) * 4, ccol = lane & 15;
    const int n = n0 + wn * 16 + ccol;
    const float Y2 = y2s[wn * 16 + ccol];
    const float bn = bias[n];
#pragma unroll
    for (int r = 0; r < 4; ++r) {
        const int ml = wm * 16 + crow + r;
        const float X2 = x2s[ml];
        const float B1 = 1.0f - c * X2;
        const float qd = acc[r];
        const float A1  = 1.0f - 2.0f * c * qd + c * Y2;
        const float den = fmaxf(1.0f - 2.0f * c * qd + c * c * X2 * Y2, 1e-15f);
        const float num2 = A1 * A1 * X2 - 2.0f * A1 * B1 * qd + B1 * B1 * Y2;
        out[(size_t)(m0 + ml) * NREL + n] = -(num2 / (den * den)) + bn;
    }
}

extern "C" void kernel_launch(void* const* d_in, const int* in_sizes, int n_in,
                              void* d_out, int out_size, void* d_ws, size_t ws_size,
                              hipStream_t stream) {
    const float* ent  = (const float*)d_in[0];   // (20000, 512)
    const float* rel  = (const float*)d_in[1];   // (512, 512)
    const int*   trip = (const int*)d_in[2];     // (1024, 3)
    const float* grot = (const float*)d_in[3];   // (256,)
    const float* bias = (const float*)d_in[4];   // (512,)
    float* out = (float*)d_out;                  // (1024, 512)

    const size_t shmem = (size_t)(64 * 512 + 32 * 512) * sizeof(_Float16)
                       + (size_t)(32 + 64) * sizeof(float);   // ~96.4 KB
    fused_kernel<<<dim3(NREL / 64, NB / 32), dim3(512), shmem, stream>>>(
        ent, rel, trip, grot, bias, out);
}

// Round 14
// 13.340 us; speedup vs baseline: 1.2405x; 1.1234x over previous
//
#include <hip/hip_runtime.h>
#include <math.h>

#define D 512
#define NREL 512
#define NB 1024

typedef _Float16 f16x8 __attribute__((ext_vector_type(8)));
typedef float f32x4 __attribute__((ext_vector_type(4)));

// tanh(x)/x and atanh(x)/x as even polynomials in u = x^2 (x = 0.1*||row|| <= ~0.05,
// u <= 0.0025; truncation error < 1e-8, fp32-exact).
__device__ __forceinline__ float tanhc(float u) {
    return 1.0f + u * (-0.33333333f + u * (0.13333333f - u * 0.05396825f));
}
__device__ __forceinline__ float atanhc(float u) {
    return 1.0f + u * (0.33333333f + u * (0.2f + u * 0.14285714f));
}

template <int N>
__device__ __forceinline__ void wave_sum_n(float* v) {
#pragma unroll
    for (int m = 1; m < 64; m <<= 1) {
#pragma unroll
        for (int i = 0; i < N; ++i) v[i] += __shfl_xor(v[i], m, 64);
    }
}

// Single dispatch: block = 32m x 64n output tile, fully self-sufficient.
// XCD-aware swizzle: xcd = bid%8 owns a 4n x 8m sub-grid -> ent/rel reads
// that are shared between blocks become XCD-L2 hits instead of IC pulls.
__global__ __launch_bounds__(512, 2) void fused_kernel(
        const float* __restrict__ ent, const float* __restrict__ rel,
        const int* __restrict__ trip, const float* __restrict__ grot,
        const float* __restrict__ bias, float* __restrict__ out) {
    extern __shared__ char smem[];
    _Float16* Bls = (_Float16*)smem;            // 64 x 512 fp16 (swizzled)
    _Float16* Als = Bls + 64 * 512;             // 32 x 512 fp16 (swizzled)
    float* x2s = (float*)(Als + 32 * 512);      // 32
    float* y2s = x2s + 32;                      // 64

    const int t = threadIdx.x, wid = t >> 6, lane = t & 63;
    // ---- XCD swizzle: bid -> (nx 0..7, my 0..31); each XCD = 4n x 8m tile --
    const int bid  = blockIdx.x;
    const int xcd  = bid & 7, slot = bid >> 3;
    const int nx   = (xcd & 1) * 4 + (slot & 3);
    const int my   = (xcd >> 1) * 8 + (slot >> 2);
    const int n0 = nx * 64;
    const int m0 = my * 32;
    const float c = 0.01f;

    // ================= phase A =================
    // rel loads first (independent, in flight early)
    float rv[8][8];
#pragma unroll
    for (int j = 0; j < 8; ++j) {
        const int r = n0 + wid * 8 + j;
        const float4 a0 = *(const float4*)(rel + (size_t)r * D + lane * 8);
        const float4 a1 = *(const float4*)(rel + (size_t)r * D + lane * 8 + 4);
        rv[j][0] = a0.x; rv[j][1] = a0.y; rv[j][2] = a0.z; rv[j][3] = a0.w;
        rv[j][4] = a1.x; rv[j][5] = a1.y; rv[j][6] = a1.z; rv[j][7] = a1.w;
    }
    // q loads
    float sv[4][8], ov[4][8];
#pragma unroll
    for (int i = 0; i < 4; ++i) {
        const int b = m0 + wid * 4 + i;
        const int si = trip[3 * b], oi = trip[3 * b + 2];
        const float4 a0 = *(const float4*)(ent + (size_t)si * D + lane * 8);
        const float4 a1 = *(const float4*)(ent + (size_t)si * D + lane * 8 + 4);
        const float4 b0 = *(const float4*)(ent + (size_t)oi * D + lane * 8);
        const float4 b1 = *(const float4*)(ent + (size_t)oi * D + lane * 8 + 4);
        sv[i][0] = a0.x; sv[i][1] = a0.y; sv[i][2] = a0.z; sv[i][3] = a0.w;
        sv[i][4] = a1.x; sv[i][5] = a1.y; sv[i][6] = a1.z; sv[i][7] = a1.w;
        ov[i][0] = b0.x; ov[i][1] = b0.y; ov[i][2] = b0.z; ov[i][3] = b0.w;
        ov[i][4] = b1.x; ov[i][5] = b1.y; ov[i][6] = b1.z; ov[i][7] = b1.w;
    }
    // rotation of raw s (ls folded in later by linearity)
    const float4 ang = *(const float4*)(grot + 4 * lane);
    const float ca0 = __cosf(ang.x), sa0 = __sinf(ang.x);
    const float ca1 = __cosf(ang.y), sa1 = __sinf(ang.y);
    const float ca2 = __cosf(ang.z), sa2 = __sinf(ang.z);
    const float ca3 = __cosf(ang.w), sa3 = __sinf(ang.w);
    float rt[4][8];
#pragma unroll
    for (int i = 0; i < 4; ++i) {
        rt[i][0] = ca0 * sv[i][0] - sa0 * sv[i][1];
        rt[i][1] = sa0 * sv[i][0] + ca0 * sv[i][1];
        rt[i][2] = ca1 * sv[i][2] - sa1 * sv[i][3];
        rt[i][3] = sa1 * sv[i][2] + ca1 * sv[i][3];
        rt[i][4] = ca2 * sv[i][4] - sa2 * sv[i][5];
        rt[i][5] = sa2 * sv[i][4] + ca2 * sv[i][5];
        rt[i][6] = ca3 * sv[i][6] - sa3 * sv[i][7];
        rt[i][7] = sa3 * sv[i][6] + ca3 * sv[i][7];
    }
    // 20 interleaved reductions: q (ss,oo,rw)x4 + rel (uu)x8
    float v[20];
#pragma unroll
    for (int i = 0; i < 4; ++i) {
        float ss = 0.f, oo = 0.f, rw = 0.f;
#pragma unroll
        for (int k = 0; k < 8; ++k) {
            ss += sv[i][k] * sv[i][k];
            oo += ov[i][k] * ov[i][k];
            rw += rt[i][k] * ov[i][k];
        }
        v[3 * i] = ss; v[3 * i + 1] = oo; v[3 * i + 2] = rw;
    }
#pragma unroll
    for (int j = 0; j < 8; ++j) {
        float uu = 0.f;
#pragma unroll
        for (int k = 0; k < 8; ++k) uu += rv[j][k] * rv[j][k];
        v[12 + j] = uu;
    }
    wave_sum_n<20>(v);

    // q scalar chains + pack + swizzled LDS store
#pragma unroll
    for (int i = 0; i < 4; ++i) {
        const float ss = v[3 * i], oo = v[3 * i + 1], rw = v[3 * i + 2];
        const float ls  = atanhc(c * ss);
        const float nu2 = ls * ls * ss;
        const float es  = tanhc(c * nu2);
        const float rr  = es * es * nu2;
        const float ro  = es * ls * rw;
        const float A1  = 1.0f - 2.0f * c * ro + c * oo;
        const float B1  = 1.0f - c * rr;
        const float den = fmaxf(1.0f - 2.0f * c * ro + c * c * rr * oo, 1e-15f);
        const float inv = 1.0f / den;
        const float qa  = -A1 * es * ls * inv;
        const float qb  = B1 * inv;
        f16x8 h;
#pragma unroll
        for (int k = 0; k < 8; ++k) h[k] = (_Float16)(qa * rt[i][k] + qb * ov[i][k]);
        const int lr = wid * 4 + i;             // local A row 0..31
        *(f16x8*)(Als + lr * 512 + ((lane * 8) ^ ((lr & 7) << 3))) = h;
        if (lane == 0)
            x2s[lr] = (A1 * A1 * rr - 2.0f * A1 * B1 * ro + B1 * B1 * oo) * inv * inv;
    }
    // rel scalar chains + pack + swizzled LDS store
#pragma unroll
    for (int j = 0; j < 8; ++j) {
        const float uu = v[12 + j];
        const float es = tanhc(c * uu);
        f16x8 h;
#pragma unroll
        for (int k = 0; k < 8; ++k) h[k] = (_Float16)(es * rv[j][k]);
        const int lr = wid * 8 + j;             // local B row 0..63
        *(f16x8*)(Bls + lr * 512 + ((lane * 8) ^ ((lr & 7) << 3))) = h;
        if (lane == 0) y2s[lr] = es * es * uu;
    }

    __syncthreads();                            // local barrier only

    // ================= phase B =================
    const int wm = wid & 1, wn = wid >> 1;      // 2m x 4n wave grid
    const int rA = wm * 16 + (lane & 15);
    const int rB = wn * 16 + (lane & 15);
    const int kg = lane >> 4;
    const _Float16* pa = Als + rA * 512;
    const _Float16* pb = Bls + rB * 512;
    const int xa = (rA & 7) << 3, xb = (rB & 7) << 3;

    f32x4 acc = {};
#pragma unroll
    for (int ks = 0; ks < 16; ++ks) {
        const int ko = ks * 32 + kg * 8;
        const f16x8 a = *(const f16x8*)(pa + (ko ^ xa));
        const f16x8 b = *(const f16x8*)(pb + (ko ^ xb));
        acc = __builtin_amdgcn_mfma_f32_16x16x32_f16(a, b, acc, 0, 0, 0);
    }

    // epilogue: C/D layout col = lane&15, row = (lane>>4)*4 + reg
    const int crow = (lane >> 4) * 4, ccol = lane & 15;
    const int n = n0 + wn * 16 + ccol;
    const float Y2 = y2s[wn * 16 + ccol];
    const float bn = bias[n];
#pragma unroll
    for (int r = 0; r < 4; ++r) {
        const int ml = wm * 16 + crow + r;
        const float X2 = x2s[ml];
        const float B1 = 1.0f - c * X2;
        const float qd = acc[r];
        const float A1  = 1.0f - 2.0f * c * qd + c * Y2;
        const float den = fmaxf(1.0f - 2.0f * c * qd + c * c * X2 * Y2, 1e-15f);
        const float num2 = A1 * A1 * X2 - 2.0f * A1 * B1 * qd + B1 * B1 * Y2;
        out[(size_t)(m0 + ml) * NREL + n] = -(num2 / (den * den)) + bn;
    }
}

extern "C" void kernel_launch(void* const* d_in, const int* in_sizes, int n_in,
                              void* d_out, int out_size, void* d_ws, size_t ws_size,
                              hipStream_t stream) {
    const float* ent  = (const float*)d_in[0];   // (20000, 512)
    const float* rel  = (const float*)d_in[1];   // (512, 512)
    const int*   trip = (const int*)d_in[2];     // (1024, 3)
    const float* grot = (const float*)d_in[3];   // (256,)
    const float* bias = (const float*)d_in[4];   // (512,)
    float* out = (float*)d_out;                  // (1024, 512)

    const size_t shmem = (size_t)(64 * 512 + 32 * 512) * sizeof(_Float16)
                       + (size_t)(32 + 64) * sizeof(float);   // ~96.4 KB
    fused_kernel<<<dim3(256), dim3(512), shmem, stream>>>(
        ent, rel, trip, grot, bias, out);
}